// Round 11
// baseline (369.526 us; speedup 1.0000x reference)
//
#include <hip/hip_runtime.h>
#include <math.h>

#define NG 110592          // 48*48*48
#define NCH 128            // conv channels
#define NKP 512
#define EPSN 1e-5f

typedef _Float16 half8 __attribute__((ext_vector_type(8)));
typedef float floatx4 __attribute__((ext_vector_type(4)));
typedef unsigned short ushort_t;

static __device__ __forceinline__ ushort_t h2u(_Float16 h) {
    union { _Float16 f; ushort_t u; } x; x.f = h; return x.u;
}

// ---------------- W prep: W0[co][ci][tap] fp32 -> Wp[slab=cc*27+tap][h][co][ci'32] f16 bits ----
__global__ __launch_bounds__(256) void k_prep_w(const float* __restrict__ W0,
                                                ushort_t* __restrict__ Wp) {
    int idx = blockIdx.x * 256 + threadIdx.x;     // 884736 total
    int s   = idx >> 13;                          // slab = cc*27 + tap
    int rem = idx & 8191;
    int h   = rem >> 12;                          // 0 = hi, 1 = lo
    int r3  = rem & 4095;
    int co  = r3 >> 5;
    int cip = r3 & 31;
    int cc  = s / 27, tap = s - cc * 27;
    int ci  = cc * 32 + cip;
    float w = W0[co * 3456 + ci * 27 + tap];
    _Float16 hi = (_Float16)w;
    Wp[idx] = (h == 0) ? h2u(hi) : h2u((_Float16)(w - (float)hi));
}

// ---------------- feats -> chunk-major channel-last f16: f16[cc][z][y][x][ci'32] ----------
__global__ __launch_bounds__(256) void k_cvt(const float* __restrict__ feats,
                                             ushort_t* __restrict__ f16) {
    int idx = blockIdx.x * 256 + threadIdx.x;     // 4*NG = 442368 exact
    int cc  = idx / NG;
    int vox = idx - cc * NG;
    int gx = vox % 48, gy = (vox / 48) % 48, gz = vox / 2304;
    const float sc = 2.0f / 47.0f;
    ushort_t* dst = f16 + (size_t)idx * 32;
    #pragma unroll
    for (int o = 0; o < 4; ++o) {
        half8 h;
        #pragma unroll
        for (int j = 0; j < 8; ++j) {
            int ci = cc * 32 + o * 8 + j;
            float v = (ci < 125) ? feats[(size_t)ci * NG + vox]
                                 : ((ci == 125 ? gx : (ci == 126 ? gy : gz)) * sc - 1.0f);
            h[j] = (_Float16)v;
        }
        *(half8*)(dst + o * 8) = h;
    }
}

// ---------------- conv3d (implicit GEMM, 1-pass f16 MFMA) + bias + relu + IN stats ----
// (unchanged from R10: 2-wave shape, 1-pass Ah*Bh, Bh register double-buffer)
__global__ __launch_bounds__(128, 2) void k_conv(const ushort_t* __restrict__ f16,
                                                 const ushort_t* __restrict__ Wp,
                                                 const float* __restrict__ b0,
                                                 float* __restrict__ yout,
                                                 float* __restrict__ gsum,
                                                 float* __restrict__ gsq) {
    __shared__ __align__(16) ushort_t hA0[14400];   // [pos 360][ci' 40] hi halves
    __shared__ float lsum[128], lsq[128];

    const int tid = threadIdx.x;
    const int blk = blockIdx.x;                     // 864: 12z*12y*6x
    const int bz = blk / 72, by = (blk % 72) / 6, bx = blk % 6;
    const int z0 = bz * 4, y0v = by * 4, x0 = bx * 8;

    const int wave = tid >> 6, lane = tid & 63;
    const int ll = lane & 15, kq = lane >> 4;
    const int chalf = wave * 64;

    lsum[tid] = 0.f; lsq[tid] = 0.f;

    int abase[8];                                   // byte offsets into halo plane
    #pragma unroll
    for (int mi = 0; mi < 8; ++mi) {
        int v = mi * 16 + ll;                       // vox 0..127
        int vz = v >> 5, vy = (v >> 3) & 3, vx = v & 7;
        abase[mi] = (vz * 60 + vy * 10 + vx) * 80 + kq * 16;
    }
    int idxh[4];                                    // half8 indices into a W slab (hi plane)
    #pragma unroll
    for (int ni = 0; ni < 4; ++ni)
        idxh[ni] = (chalf + ni * 16 + ll) * 4 + kq;

    floatx4 acc[8][4];
    const floatx4 zz = {0.f, 0.f, 0.f, 0.f};
    #pragma unroll
    for (int mi = 0; mi < 8; ++mi)
        #pragma unroll
        for (int ni = 0; ni < 4; ++ni) acc[mi][ni] = zz;

    // prologue: slab 0's B-hi frags
    half8 Bh[4];
    {
        const half8* bp = (const half8*)Wp;
        #pragma unroll
        for (int ni = 0; ni < 4; ++ni) Bh[ni] = bp[idxh[ni]];
    }

    for (int cc = 0; cc < 4; ++cc) {
        __syncthreads();
        // ---- stage halo chunk: pure b128 copy from pre-converted f16 ----
        for (int u = tid; u < 1440; u += 128) {
            int pos = u >> 2, c8 = u & 3;           // 4 lanes cover one pos's 64 B
            int zi = pos / 60, rem = pos - zi * 60;
            int yi = rem / 10, xi = rem - yi * 10;
            int gz = z0 - 1 + zi, gy = y0v - 1 + yi, gx = x0 - 1 + xi;
            bool inb = ((unsigned)gz < 48u) & ((unsigned)gy < 48u) & ((unsigned)gx < 48u);
            half8 h;
            #pragma unroll
            for (int j = 0; j < 8; ++j) h[j] = (_Float16)0.f;
            if (inb) {
                size_t off = ((size_t)(cc * NG + gz * 2304 + gy * 48 + gx)) * 32 + c8 * 8;
                h = *(const half8*)(f16 + off);
            }
            *(half8*)(&hA0[pos * 40 + c8 * 8]) = h;
        }
        __syncthreads();

        for (int tap = 0; tap < 27; ++tap) {
            const int it = cc * 27 + tap;
            // ---- issue NEXT slab's B-hi loads (register double-buffer) ----
            int itn = it + 1; if (itn > 107) itn = 107;
            const half8* bpn = (const half8*)(Wp + (size_t)itn * 8192);
            half8 Bhn[4];
            #pragma unroll
            for (int ni = 0; ni < 4; ++ni) Bhn[ni] = bpn[idxh[ni]];

            // ---- A frags for current tap from LDS (8 ds_read_b128) ----
            const int tb = (tap / 9) * 4800 + ((tap / 3) % 3) * 800 + (tap % 3) * 80;
            half8 Ah[8];
            #pragma unroll
            for (int mi = 0; mi < 8; ++mi)
                Ah[mi] = *(const half8*)((const char*)hA0 + (abase[mi] + tb));

            // ---- single pass: Ah x Bh ----
            #pragma unroll
            for (int mi = 0; mi < 8; ++mi)
                #pragma unroll
                for (int ni = 0; ni < 4; ++ni)
                    acc[mi][ni] = __builtin_amdgcn_mfma_f32_16x16x32_f16(Ah[mi], Bh[ni], acc[mi][ni], 0, 0, 0);

            #pragma unroll
            for (int ni = 0; ni < 4; ++ni) Bh[ni] = Bhn[ni];
        }
    }

    // ---- epilogue: bias + relu + store + per-channel stats ----
    #pragma unroll
    for (int ni = 0; ni < 4; ++ni) {
        int co = chalf + ni * 16 + ll;
        float b = b0[co];
        float s = 0.f, q = 0.f;
        #pragma unroll
        for (int mi = 0; mi < 8; ++mi) {
            #pragma unroll
            for (int r = 0; r < 4; ++r) {
                int v = mi * 16 + kq * 4 + r;       // C/D: row=(lane>>4)*4+r
                int vz = v >> 5, vy = (v >> 3) & 3, vx = v & 7;
                float val = acc[mi][ni][r] + b;
                val = val > 0.f ? val : 0.f;
                yout[(size_t)co * NG + (z0 + vz) * 2304 + (y0v + vy) * 48 + (x0 + vx)] = val;
                s += val; q += val * val;
            }
        }
        atomicAdd(&lsum[co], s);
        atomicAdd(&lsq[co], q);
    }
    __syncthreads();
    if (wave == 0) {
        atomicAdd(&gsum[tid + 0],  lsum[tid + 0]);
        atomicAdd(&gsq[tid + 0],   lsq[tid + 0]);
        atomicAdd(&gsum[tid + 64], lsum[tid + 64]);
        atomicAdd(&gsq[tid + 64],  lsq[tid + 64]);
    }
}

// ---------------- finalize instance-norm params ----------------
__global__ void k_finalize(const float* __restrict__ gsum, const float* __restrict__ gsq,
                           float* __restrict__ mu, float* __restrict__ inv) {
    int c = threadIdx.x;
    float m = gsum[c] * (1.0f / NG);
    float v = gsq[c] * (1.0f / NG) - m * m;
    mu[c] = m;
    inv[c] = rsqrtf(v + EPSN);
}

// ---------------- sample fk at keypoints: normalized, split-f16, A-frag layout + ||fk||^2 ----
__global__ __launch_bounds__(128) void k_sample(const float* __restrict__ kpts,
                                                const float* __restrict__ yin,
                                                const float* __restrict__ mu,
                                                const float* __restrict__ inv,
                                                ushort_t* __restrict__ fkH,
                                                ushort_t* __restrict__ fkL,
                                                float* __restrict__ fkn2) {
    __shared__ float red[128];
    const int n = blockIdx.x, c = threadIdx.x;
    float px = kpts[n * 3 + 0], py = kpts[n * 3 + 1], pz = kpts[n * 3 + 2];
    float ix = (px + 1.f) * 0.5f * 47.f;
    float iy = (py + 1.f) * 0.5f * 47.f;
    float iz = (pz + 1.f) * 0.5f * 47.f;
    float xf = floorf(ix), yf = floorf(iy), zf = floorf(iz);
    float wx = ix - xf, wy = iy - yf, wz = iz - zf;
    int x0 = min(max((int)xf, 0), 47), y0 = min(max((int)yf, 0), 47), z0 = min(max((int)zf, 0), 47);
    int x1 = min(x0 + 1, 47), y1 = min(y0 + 1, 47), z1 = min(z0 + 1, 47);

    const float* base = yin + (size_t)c * NG;
    float v000 = base[z0 * 2304 + y0 * 48 + x0];
    float v001 = base[z0 * 2304 + y0 * 48 + x1];
    float v010 = base[z0 * 2304 + y1 * 48 + x0];
    float v011 = base[z0 * 2304 + y1 * 48 + x1];
    float v100 = base[z1 * 2304 + y0 * 48 + x0];
    float v101 = base[z1 * 2304 + y0 * 48 + x1];
    float v110 = base[z1 * 2304 + y1 * 48 + x0];
    float v111 = base[z1 * 2304 + y1 * 48 + x1];

    float val = v000 * (1 - wz) * (1 - wy) * (1 - wx)
              + v001 * (1 - wz) * (1 - wy) * wx
              + v010 * (1 - wz) * wy * (1 - wx)
              + v011 * (1 - wz) * wy * wx
              + v100 * wz * (1 - wy) * (1 - wx)
              + v101 * wz * (1 - wy) * wx
              + v110 * wz * wy * (1 - wx)
              + v111 * wz * wy * wx;

    val = (val - mu[c]) * inv[c];
    _Float16 h = (_Float16)val;
    fkH[n * 128 + c] = h2u(h);
    fkL[n * 128 + c] = h2u((_Float16)(val - (float)h));
    red[c] = val * val;
    __syncthreads();
    for (int s = 64; s > 0; s >>= 1) {
        if (c < s) red[c] += red[c + s];
        __syncthreads();
    }
    if (c == 0) fkn2[n] = red[0];
}

// ---------------- MFMA flash-attention over keypoints + disp reduce ----------------
// R11: each wave's 128 keys split into TWO 64-key passes -> acc 64 AGPR, peak ~140
// unified regs -> launch_bounds(256,3) gives 3 waves/SIMD (was 2 at acc=128).
// 8 partials (4 waves x 2 passes) merged through LDS. Numerics unchanged (3-pass).
__global__ __launch_bounds__(256, 3) void k_attn(const float* __restrict__ yb,
                                                 const float* __restrict__ mu,
                                                 const float* __restrict__ inv,
                                                 const ushort_t* __restrict__ fkH,
                                                 const ushort_t* __restrict__ fkL,
                                                 const float* __restrict__ fk2,
                                                 const float* __restrict__ disp,
                                                 float* __restrict__ out) {
    __shared__ __align__(16) ushort_t fgH[64 * 136];   // [vox][ch'] hi   17.4 KB
    __shared__ __align__(16) ushort_t fgL[64 * 136];   // lo              17.4 KB
    __shared__ float dspx[512], dspy[512], dspz[512];  // 6 KB
    __shared__ float mrg[64 * 8 * 5];                  // [vox][wave*2+pass][{m,l,p3}] 10.2 KB

    const int tid = threadIdx.x;
    const int gbase = blockIdx.x * 64;
    const int wave = tid >> 6, lane = tid & 63;
    const int ll = lane & 15, kq = lane >> 4;

    {
        int v = tid & 63;
        int c0 = (tid >> 6) * 32;
        #pragma unroll
        for (int o = 0; o < 4; ++o) {
            half8 h, l;
            #pragma unroll
            for (int j = 0; j < 8; ++j) {
                int c = c0 + o * 8 + j;
                float x = yb[(size_t)c * NG + gbase + v];
                x = (x - mu[c]) * inv[c];
                _Float16 hh = (_Float16)x;
                h[j] = hh;
                l[j] = (_Float16)(x - (float)hh);
            }
            *(half8*)&fgH[v * 136 + c0 + o * 8] = h;
            *(half8*)&fgL[v * 136 + c0 + o * 8] = l;
        }
    }
    for (int s = tid; s < 512; s += 256) {
        dspx[s] = disp[3 * s + 0];
        dspy[s] = disp[3 * s + 1];
        dspz[s] = disp[3 * s + 2];
    }
    __syncthreads();

    for (int pass = 0; pass < 2; ++pass) {
        const int key0 = (wave * 2 + pass) * 64;

        floatx4 acc[4][4];
        const floatx4 zz = {0.f, 0.f, 0.f, 0.f};
        #pragma unroll
        for (int mi = 0; mi < 4; ++mi)
            #pragma unroll
            for (int ni = 0; ni < 4; ++ni) acc[mi][ni] = zz;

        #pragma unroll
        for (int ks = 0; ks < 4; ++ks) {
            half8 Bh[4], Bl[4];
            #pragma unroll
            for (int ni = 0; ni < 4; ++ni) {
                int ad = (ni * 16 + ll) * 136 + ks * 32 + kq * 8;
                Bh[ni] = *(const half8*)&fgH[ad];
                Bl[ni] = *(const half8*)&fgL[ad];
            }
            #pragma unroll
            for (int mi = 0; mi < 4; ++mi) {
                int key = key0 + mi * 16 + ll;
                int ga = key * 128 + ks * 32 + kq * 8;
                half8 Ah = *(const half8*)&fkH[ga];
                half8 Al = *(const half8*)&fkL[ga];
                #pragma unroll
                for (int ni = 0; ni < 4; ++ni) {
                    acc[mi][ni] = __builtin_amdgcn_mfma_f32_16x16x32_f16(Ah, Bh[ni], acc[mi][ni], 0, 0, 0);
                    acc[mi][ni] = __builtin_amdgcn_mfma_f32_16x16x32_f16(Ah, Bl[ni], acc[mi][ni], 0, 0, 0);
                    acc[mi][ni] = __builtin_amdgcn_mfma_f32_16x16x32_f16(Al, Bh[ni], acc[mi][ni], 0, 0, 0);
                }
            }
        }

        // ---- logits = 2*cross - ||fk||^2; per-vox max over this pass's 64 keys ----
        float mx[4] = {-1e30f, -1e30f, -1e30f, -1e30f};
        #pragma unroll
        for (int mi = 0; mi < 4; ++mi)
            #pragma unroll
            for (int r = 0; r < 4; ++r) {
                int key = key0 + mi * 16 + kq * 4 + r;
                float f2 = fk2[key];
                #pragma unroll
                for (int ni = 0; ni < 4; ++ni) {
                    float s = 2.f * acc[mi][ni][r] - f2;
                    acc[mi][ni][r] = s;
                    mx[ni] = fmaxf(mx[ni], s);
                }
            }
        #pragma unroll
        for (int ni = 0; ni < 4; ++ni) {
            mx[ni] = fmaxf(mx[ni], __shfl_xor(mx[ni], 16, 64));
            mx[ni] = fmaxf(mx[ni], __shfl_xor(mx[ni], 32, 64));
        }

        float lv[4]  = {0.f, 0.f, 0.f, 0.f};
        float pxv[4] = {0.f, 0.f, 0.f, 0.f};
        float pyv[4] = {0.f, 0.f, 0.f, 0.f};
        float pzv[4] = {0.f, 0.f, 0.f, 0.f};
        #pragma unroll
        for (int mi = 0; mi < 4; ++mi)
            #pragma unroll
            for (int r = 0; r < 4; ++r) {
                int key = key0 + mi * 16 + kq * 4 + r;
                float dx = dspx[key], dy = dspy[key], dz = dspz[key];
                #pragma unroll
                for (int ni = 0; ni < 4; ++ni) {
                    float p = __expf(acc[mi][ni][r] - mx[ni]);
                    lv[ni] += p;
                    pxv[ni] = fmaf(p, dx, pxv[ni]);
                    pyv[ni] = fmaf(p, dy, pyv[ni]);
                    pzv[ni] = fmaf(p, dz, pzv[ni]);
                }
            }
        #pragma unroll
        for (int ni = 0; ni < 4; ++ni) {
            lv[ni]  += __shfl_xor(lv[ni], 16, 64);  lv[ni]  += __shfl_xor(lv[ni], 32, 64);
            pxv[ni] += __shfl_xor(pxv[ni], 16, 64); pxv[ni] += __shfl_xor(pxv[ni], 32, 64);
            pyv[ni] += __shfl_xor(pyv[ni], 16, 64); pyv[ni] += __shfl_xor(pyv[ni], 32, 64);
            pzv[ni] += __shfl_xor(pzv[ni], 16, 64); pzv[ni] += __shfl_xor(pzv[ni], 32, 64);
        }

        if (kq == 0) {
            #pragma unroll
            for (int ni = 0; ni < 4; ++ni) {
                int vox = ni * 16 + ll;
                float* q = &mrg[(vox * 8 + wave * 2 + pass) * 5];
                q[0] = mx[ni]; q[1] = lv[ni]; q[2] = pxv[ni]; q[3] = pyv[ni]; q[4] = pzv[ni];
            }
        }
    }
    __syncthreads();

    if (tid < 64) {
        float M = -1e30f;
        #pragma unroll
        for (int w = 0; w < 8; ++w) M = fmaxf(M, mrg[(tid * 8 + w) * 5]);
        float L = 0.f, X = 0.f, Y = 0.f, Z = 0.f;
        #pragma unroll
        for (int w = 0; w < 8; ++w) {
            const float* q = &mrg[(tid * 8 + w) * 5];
            float a = __expf(q[0] - M);
            L = fmaf(q[1], a, L);
            X = fmaf(q[2], a, X);
            Y = fmaf(q[3], a, Y);
            Z = fmaf(q[4], a, Z);
        }
        float il = 1.0f / L;
        out[0 * NG + gbase + tid] = X * il;
        out[1 * NG + gbase + tid] = Y * il;
        out[2 * NG + gbase + tid] = Z * il;
    }
}

extern "C" void kernel_launch(void* const* d_in, const int* in_sizes, int n_in,
                              void* d_out, int out_size, void* d_ws, size_t ws_size,
                              hipStream_t stream) {
    const float* kpts  = (const float*)d_in[0];   // (1,512,3)
    const float* disp  = (const float*)d_in[1];   // (1,512,3)
    const float* feats = (const float*)d_in[2];   // (1,125,48,48,48)
    const float* W0    = (const float*)d_in[3];   // (128,128,3,3,3)
    const float* b0    = (const float*)d_in[4];   // (128,)

    float* ws = (float*)d_ws;
    float*    yb   = ws;                                   // 128*110592 floats
    ushort_t* Wp   = (ushort_t*)(yb + (size_t)NCH * NG);   // 884736 u16 (= 442368 f32 slots)
    float*    gsum = yb + (size_t)NCH * NG + 442368;       // 128
    float*    gsq  = gsum + 128;                           // 128
    float*    mu   = gsq + 128;                            // 128
    float*    ivr  = mu + 128;                             // 128
    float*    fk2  = ivr + 128;                            // 512
    ushort_t* fkH  = (ushort_t*)(fk2 + 512);               // 65536 u16
    ushort_t* fkL  = fkH + 65536;                          // 65536 u16
    ushort_t* f16  = fkL + 65536;                          // 4*NG*32 u16 = 28.3 MB

    k_prep_w<<<3456, 256, 0, stream>>>(W0, Wp);
    k_cvt<<<1728, 256, 0, stream>>>(feats, f16);
    hipMemsetAsync(gsum, 0, 256 * sizeof(float), stream);
    k_conv<<<864, 128, 0, stream>>>(f16, Wp, b0, yb, gsum, gsq);
    k_finalize<<<1, 128, 0, stream>>>(gsum, gsq, mu, ivr);
    k_sample<<<NKP, 128, 0, stream>>>(kpts, yb, mu, ivr, fkH, fkL, fk2);
    k_attn<<<1728, 256, 0, stream>>>(yb, mu, ivr, fkH, fkL, fk2, disp, (float*)d_out);
}

// Round 12
// 279.495 us; speedup vs baseline: 1.3221x; 1.3221x over previous
//
#include <hip/hip_runtime.h>
#include <math.h>

#define NG 110592          // 48*48*48
#define NCH 128            // conv channels
#define NKP 512
#define EPSN 1e-5f

typedef _Float16 half8 __attribute__((ext_vector_type(8)));
typedef float floatx4 __attribute__((ext_vector_type(4)));
typedef unsigned short ushort_t;

static __device__ __forceinline__ ushort_t h2u(_Float16 h) {
    union { _Float16 f; ushort_t u; } x; x.f = h; return x.u;
}

// ---------------- W prep: W0[co][ci][tap] fp32 -> Wp[slab=cc*27+tap][h][co][ci'32] f16 bits ----
__global__ __launch_bounds__(256) void k_prep_w(const float* __restrict__ W0,
                                                ushort_t* __restrict__ Wp) {
    int idx = blockIdx.x * 256 + threadIdx.x;     // 884736 total
    int s   = idx >> 13;                          // slab = cc*27 + tap
    int rem = idx & 8191;
    int h   = rem >> 12;                          // 0 = hi, 1 = lo
    int r3  = rem & 4095;
    int co  = r3 >> 5;
    int cip = r3 & 31;
    int cc  = s / 27, tap = s - cc * 27;
    int ci  = cc * 32 + cip;
    float w = W0[co * 3456 + ci * 27 + tap];
    _Float16 hi = (_Float16)w;
    Wp[idx] = (h == 0) ? h2u(hi) : h2u((_Float16)(w - (float)hi));
}

// ---------------- feats -> chunk-major channel-last f16: f16[cc][z][y][x][ci'32] ----------
__global__ __launch_bounds__(256) void k_cvt(const float* __restrict__ feats,
                                             ushort_t* __restrict__ f16) {
    int idx = blockIdx.x * 256 + threadIdx.x;     // 4*NG = 442368 exact
    int cc  = idx / NG;
    int vox = idx - cc * NG;
    int gx = vox % 48, gy = (vox / 48) % 48, gz = vox / 2304;
    const float sc = 2.0f / 47.0f;
    ushort_t* dst = f16 + (size_t)idx * 32;
    #pragma unroll
    for (int o = 0; o < 4; ++o) {
        half8 h;
        #pragma unroll
        for (int j = 0; j < 8; ++j) {
            int ci = cc * 32 + o * 8 + j;
            float v = (ci < 125) ? feats[(size_t)ci * NG + vox]
                                 : ((ci == 125 ? gx : (ci == 126 ? gy : gz)) * sc - 1.0f);
            h[j] = (_Float16)v;
        }
        *(half8*)(dst + o * 8) = h;
    }
}

// ---------------- conv3d (implicit GEMM, 1-pass f16 MFMA) + bias + relu + IN stats ----
// (unchanged from R10: 2-wave shape, 1-pass Ah*Bh, Bh register double-buffer)
__global__ __launch_bounds__(128, 2) void k_conv(const ushort_t* __restrict__ f16,
                                                 const ushort_t* __restrict__ Wp,
                                                 const float* __restrict__ b0,
                                                 float* __restrict__ yout,
                                                 float* __restrict__ gsum,
                                                 float* __restrict__ gsq) {
    __shared__ __align__(16) ushort_t hA0[14400];   // [pos 360][ci' 40] hi halves
    __shared__ float lsum[128], lsq[128];

    const int tid = threadIdx.x;
    const int blk = blockIdx.x;                     // 864: 12z*12y*6x
    const int bz = blk / 72, by = (blk % 72) / 6, bx = blk % 6;
    const int z0 = bz * 4, y0v = by * 4, x0 = bx * 8;

    const int wave = tid >> 6, lane = tid & 63;
    const int ll = lane & 15, kq = lane >> 4;
    const int chalf = wave * 64;

    lsum[tid] = 0.f; lsq[tid] = 0.f;

    int abase[8];                                   // byte offsets into halo plane
    #pragma unroll
    for (int mi = 0; mi < 8; ++mi) {
        int v = mi * 16 + ll;                       // vox 0..127
        int vz = v >> 5, vy = (v >> 3) & 3, vx = v & 7;
        abase[mi] = (vz * 60 + vy * 10 + vx) * 80 + kq * 16;
    }
    int idxh[4];                                    // half8 indices into a W slab (hi plane)
    #pragma unroll
    for (int ni = 0; ni < 4; ++ni)
        idxh[ni] = (chalf + ni * 16 + ll) * 4 + kq;

    floatx4 acc[8][4];
    const floatx4 zz = {0.f, 0.f, 0.f, 0.f};
    #pragma unroll
    for (int mi = 0; mi < 8; ++mi)
        #pragma unroll
        for (int ni = 0; ni < 4; ++ni) acc[mi][ni] = zz;

    // prologue: slab 0's B-hi frags
    half8 Bh[4];
    {
        const half8* bp = (const half8*)Wp;
        #pragma unroll
        for (int ni = 0; ni < 4; ++ni) Bh[ni] = bp[idxh[ni]];
    }

    for (int cc = 0; cc < 4; ++cc) {
        __syncthreads();
        // ---- stage halo chunk: pure b128 copy from pre-converted f16 ----
        for (int u = tid; u < 1440; u += 128) {
            int pos = u >> 2, c8 = u & 3;           // 4 lanes cover one pos's 64 B
            int zi = pos / 60, rem = pos - zi * 60;
            int yi = rem / 10, xi = rem - yi * 10;
            int gz = z0 - 1 + zi, gy = y0v - 1 + yi, gx = x0 - 1 + xi;
            bool inb = ((unsigned)gz < 48u) & ((unsigned)gy < 48u) & ((unsigned)gx < 48u);
            half8 h;
            #pragma unroll
            for (int j = 0; j < 8; ++j) h[j] = (_Float16)0.f;
            if (inb) {
                size_t off = ((size_t)(cc * NG + gz * 2304 + gy * 48 + gx)) * 32 + c8 * 8;
                h = *(const half8*)(f16 + off);
            }
            *(half8*)(&hA0[pos * 40 + c8 * 8]) = h;
        }
        __syncthreads();

        for (int tap = 0; tap < 27; ++tap) {
            const int it = cc * 27 + tap;
            // ---- issue NEXT slab's B-hi loads (register double-buffer) ----
            int itn = it + 1; if (itn > 107) itn = 107;
            const half8* bpn = (const half8*)(Wp + (size_t)itn * 8192);
            half8 Bhn[4];
            #pragma unroll
            for (int ni = 0; ni < 4; ++ni) Bhn[ni] = bpn[idxh[ni]];

            // ---- A frags for current tap from LDS (8 ds_read_b128) ----
            const int tb = (tap / 9) * 4800 + ((tap / 3) % 3) * 800 + (tap % 3) * 80;
            half8 Ah[8];
            #pragma unroll
            for (int mi = 0; mi < 8; ++mi)
                Ah[mi] = *(const half8*)((const char*)hA0 + (abase[mi] + tb));

            // ---- single pass: Ah x Bh ----
            #pragma unroll
            for (int mi = 0; mi < 8; ++mi)
                #pragma unroll
                for (int ni = 0; ni < 4; ++ni)
                    acc[mi][ni] = __builtin_amdgcn_mfma_f32_16x16x32_f16(Ah[mi], Bh[ni], acc[mi][ni], 0, 0, 0);

            #pragma unroll
            for (int ni = 0; ni < 4; ++ni) Bh[ni] = Bhn[ni];
        }
    }

    // ---- epilogue: bias + relu + store + per-channel stats ----
    #pragma unroll
    for (int ni = 0; ni < 4; ++ni) {
        int co = chalf + ni * 16 + ll;
        float b = b0[co];
        float s = 0.f, q = 0.f;
        #pragma unroll
        for (int mi = 0; mi < 8; ++mi) {
            #pragma unroll
            for (int r = 0; r < 4; ++r) {
                int v = mi * 16 + kq * 4 + r;       // C/D: row=(lane>>4)*4+r
                int vz = v >> 5, vy = (v >> 3) & 3, vx = v & 7;
                float val = acc[mi][ni][r] + b;
                val = val > 0.f ? val : 0.f;
                yout[(size_t)co * NG + (z0 + vz) * 2304 + (y0v + vy) * 48 + (x0 + vx)] = val;
                s += val; q += val * val;
            }
        }
        atomicAdd(&lsum[co], s);
        atomicAdd(&lsq[co], q);
    }
    __syncthreads();
    if (wave == 0) {
        atomicAdd(&gsum[tid + 0],  lsum[tid + 0]);
        atomicAdd(&gsq[tid + 0],   lsq[tid + 0]);
        atomicAdd(&gsum[tid + 64], lsum[tid + 64]);
        atomicAdd(&gsq[tid + 64],  lsq[tid + 64]);
    }
}

// ---------------- finalize instance-norm params ----------------
__global__ void k_finalize(const float* __restrict__ gsum, const float* __restrict__ gsq,
                           float* __restrict__ mu, float* __restrict__ inv) {
    int c = threadIdx.x;
    float m = gsum[c] * (1.0f / NG);
    float v = gsq[c] * (1.0f / NG) - m * m;
    mu[c] = m;
    inv[c] = rsqrtf(v + EPSN);
}

// ---------------- sample fk at keypoints: normalized f16-hi, A-frag layout + ||fk||^2 ----
__global__ __launch_bounds__(128) void k_sample(const float* __restrict__ kpts,
                                                const float* __restrict__ yin,
                                                const float* __restrict__ mu,
                                                const float* __restrict__ inv,
                                                ushort_t* __restrict__ fkH,
                                                float* __restrict__ fkn2) {
    __shared__ float red[128];
    const int n = blockIdx.x, c = threadIdx.x;
    float px = kpts[n * 3 + 0], py = kpts[n * 3 + 1], pz = kpts[n * 3 + 2];
    float ix = (px + 1.f) * 0.5f * 47.f;
    float iy = (py + 1.f) * 0.5f * 47.f;
    float iz = (pz + 1.f) * 0.5f * 47.f;
    float xf = floorf(ix), yf = floorf(iy), zf = floorf(iz);
    float wx = ix - xf, wy = iy - yf, wz = iz - zf;
    int x0 = min(max((int)xf, 0), 47), y0 = min(max((int)yf, 0), 47), z0 = min(max((int)zf, 0), 47);
    int x1 = min(x0 + 1, 47), y1 = min(y0 + 1, 47), z1 = min(z0 + 1, 47);

    const float* base = yin + (size_t)c * NG;
    float v000 = base[z0 * 2304 + y0 * 48 + x0];
    float v001 = base[z0 * 2304 + y0 * 48 + x1];
    float v010 = base[z0 * 2304 + y1 * 48 + x0];
    float v011 = base[z0 * 2304 + y1 * 48 + x1];
    float v100 = base[z1 * 2304 + y0 * 48 + x0];
    float v101 = base[z1 * 2304 + y0 * 48 + x1];
    float v110 = base[z1 * 2304 + y1 * 48 + x0];
    float v111 = base[z1 * 2304 + y1 * 48 + x1];

    float val = v000 * (1 - wz) * (1 - wy) * (1 - wx)
              + v001 * (1 - wz) * (1 - wy) * wx
              + v010 * (1 - wz) * wy * (1 - wx)
              + v011 * (1 - wz) * wy * wx
              + v100 * wz * (1 - wy) * (1 - wx)
              + v101 * wz * (1 - wy) * wx
              + v110 * wz * wy * (1 - wx)
              + v111 * wz * wy * wx;

    val = (val - mu[c]) * inv[c];
    fkH[n * 128 + c] = h2u((_Float16)val);
    red[c] = val * val;
    __syncthreads();
    for (int s = 64; s > 0; s >>= 1) {
        if (c < s) red[c] += red[c + s];
        __syncthreads();
    }
    if (c == 0) fkn2[n] = red[0];
}

// ---------------- MFMA flash-attention over keypoints + disp reduce ----------------
// R12: R10 shape (acc[8][4], LB(256,2) - known no-spill) with 2-pass split-f16:
// cross = fkH*(fgH+fgL) = fkH*fg. Dropped fkL*fgH term ~5e-3 logit error.
// fk gather traffic halves (no fkL); MFMA 384->256/wave.
__global__ __launch_bounds__(256, 2) void k_attn(const float* __restrict__ yb,
                                                 const float* __restrict__ mu,
                                                 const float* __restrict__ inv,
                                                 const ushort_t* __restrict__ fkH,
                                                 const float* __restrict__ fk2,
                                                 const float* __restrict__ disp,
                                                 float* __restrict__ out) {
    __shared__ __align__(16) ushort_t fgH[64 * 136];   // [vox][ch'] hi
    __shared__ __align__(16) ushort_t fgL[64 * 136];   // lo
    __shared__ float dspx[512], dspy[512], dspz[512];
    __shared__ float fk2s[512];
    __shared__ float mrg[64 * 4 * 5];                  // [vox][wave][{m,l,px,py,pz}]

    const int tid = threadIdx.x;
    const int gbase = blockIdx.x * 64;
    const int wave = tid >> 6, lane = tid & 63;
    const int ll = lane & 15, kq = lane >> 4;

    {
        int v = tid & 63;
        int c0 = (tid >> 6) * 32;
        #pragma unroll
        for (int o = 0; o < 4; ++o) {
            half8 h, l;
            #pragma unroll
            for (int j = 0; j < 8; ++j) {
                int c = c0 + o * 8 + j;
                float x = yb[(size_t)c * NG + gbase + v];
                x = (x - mu[c]) * inv[c];
                _Float16 hh = (_Float16)x;
                h[j] = hh;
                l[j] = (_Float16)(x - (float)hh);
            }
            *(half8*)&fgH[v * 136 + c0 + o * 8] = h;
            *(half8*)&fgL[v * 136 + c0 + o * 8] = l;
        }
    }
    for (int s = tid; s < 512; s += 256) {
        dspx[s] = disp[3 * s + 0];
        dspy[s] = disp[3 * s + 1];
        dspz[s] = disp[3 * s + 2];
        fk2s[s] = fk2[s];
    }
    __syncthreads();

    const int key0 = wave * 128;

    floatx4 acc[8][4];
    const floatx4 zz = {0.f, 0.f, 0.f, 0.f};
    #pragma unroll
    for (int mi = 0; mi < 8; ++mi)
        #pragma unroll
        for (int ni = 0; ni < 4; ++ni) acc[mi][ni] = zz;

    #pragma unroll
    for (int ks = 0; ks < 4; ++ks) {
        half8 Bh[4], Bl[4];
        #pragma unroll
        for (int ni = 0; ni < 4; ++ni) {
            int ad = (ni * 16 + ll) * 136 + ks * 32 + kq * 8;
            Bh[ni] = *(const half8*)&fgH[ad];
            Bl[ni] = *(const half8*)&fgL[ad];
        }
        #pragma unroll
        for (int mi = 0; mi < 8; ++mi) {
            int key = key0 + mi * 16 + ll;
            int ga = key * 128 + ks * 32 + kq * 8;
            half8 Ah = *(const half8*)&fkH[ga];
            #pragma unroll
            for (int ni = 0; ni < 4; ++ni) {
                acc[mi][ni] = __builtin_amdgcn_mfma_f32_16x16x32_f16(Ah, Bh[ni], acc[mi][ni], 0, 0, 0);
                acc[mi][ni] = __builtin_amdgcn_mfma_f32_16x16x32_f16(Ah, Bl[ni], acc[mi][ni], 0, 0, 0);
            }
        }
    }

    float mx[4] = {-1e30f, -1e30f, -1e30f, -1e30f};
    #pragma unroll
    for (int mi = 0; mi < 8; ++mi)
        #pragma unroll
        for (int r = 0; r < 4; ++r) {
            int key = key0 + mi * 16 + kq * 4 + r;
            float f2 = fk2s[key];
            #pragma unroll
            for (int ni = 0; ni < 4; ++ni) {
                float s = 2.f * acc[mi][ni][r] - f2;
                acc[mi][ni][r] = s;
                mx[ni] = fmaxf(mx[ni], s);
            }
        }
    #pragma unroll
    for (int ni = 0; ni < 4; ++ni) {
        mx[ni] = fmaxf(mx[ni], __shfl_xor(mx[ni], 16, 64));
        mx[ni] = fmaxf(mx[ni], __shfl_xor(mx[ni], 32, 64));
    }

    float lv[4] = {0.f, 0.f, 0.f, 0.f};
    float pxv[4] = {0.f, 0.f, 0.f, 0.f};
    float pyv[4] = {0.f, 0.f, 0.f, 0.f};
    float pzv[4] = {0.f, 0.f, 0.f, 0.f};
    #pragma unroll
    for (int mi = 0; mi < 8; ++mi)
        #pragma unroll
        for (int r = 0; r < 4; ++r) {
            int key = key0 + mi * 16 + kq * 4 + r;
            float dx = dspx[key], dy = dspy[key], dz = dspz[key];
            #pragma unroll
            for (int ni = 0; ni < 4; ++ni) {
                float p = __expf(acc[mi][ni][r] - mx[ni]);
                lv[ni] += p;
                pxv[ni] = fmaf(p, dx, pxv[ni]);
                pyv[ni] = fmaf(p, dy, pyv[ni]);
                pzv[ni] = fmaf(p, dz, pzv[ni]);
            }
        }
    #pragma unroll
    for (int ni = 0; ni < 4; ++ni) {
        lv[ni]  += __shfl_xor(lv[ni], 16, 64);  lv[ni]  += __shfl_xor(lv[ni], 32, 64);
        pxv[ni] += __shfl_xor(pxv[ni], 16, 64); pxv[ni] += __shfl_xor(pxv[ni], 32, 64);
        pyv[ni] += __shfl_xor(pyv[ni], 16, 64); pyv[ni] += __shfl_xor(pyv[ni], 32, 64);
        pzv[ni] += __shfl_xor(pzv[ni], 16, 64); pzv[ni] += __shfl_xor(pzv[ni], 32, 64);
    }

    if (kq == 0) {
        #pragma unroll
        for (int ni = 0; ni < 4; ++ni) {
            int vox = ni * 16 + ll;
            float* q = &mrg[(vox * 4 + wave) * 5];
            q[0] = mx[ni]; q[1] = lv[ni]; q[2] = pxv[ni]; q[3] = pyv[ni]; q[4] = pzv[ni];
        }
    }
    __syncthreads();

    if (tid < 64) {
        float M = -1e30f;
        #pragma unroll
        for (int w = 0; w < 4; ++w) M = fmaxf(M, mrg[(tid * 4 + w) * 5]);
        float L = 0.f, X = 0.f, Y = 0.f, Z = 0.f;
        #pragma unroll
        for (int w = 0; w < 4; ++w) {
            const float* q = &mrg[(tid * 4 + w) * 5];
            float a = __expf(q[0] - M);
            L = fmaf(q[1], a, L);
            X = fmaf(q[2], a, X);
            Y = fmaf(q[3], a, Y);
            Z = fmaf(q[4], a, Z);
        }
        float il = 1.0f / L;
        out[0 * NG + gbase + tid] = X * il;
        out[1 * NG + gbase + tid] = Y * il;
        out[2 * NG + gbase + tid] = Z * il;
    }
}

extern "C" void kernel_launch(void* const* d_in, const int* in_sizes, int n_in,
                              void* d_out, int out_size, void* d_ws, size_t ws_size,
                              hipStream_t stream) {
    const float* kpts  = (const float*)d_in[0];   // (1,512,3)
    const float* disp  = (const float*)d_in[1];   // (1,512,3)
    const float* feats = (const float*)d_in[2];   // (1,125,48,48,48)
    const float* W0    = (const float*)d_in[3];   // (128,128,3,3,3)
    const float* b0    = (const float*)d_in[4];   // (128,)

    float* ws = (float*)d_ws;
    float*    yb   = ws;                                   // 128*110592 floats
    ushort_t* Wp   = (ushort_t*)(yb + (size_t)NCH * NG);   // 884736 u16 (= 442368 f32 slots)
    float*    gsum = yb + (size_t)NCH * NG + 442368;       // 128
    float*    gsq  = gsum + 128;                           // 128
    float*    mu   = gsq + 128;                            // 128
    float*    ivr  = mu + 128;                             // 128
    float*    fk2  = ivr + 128;                            // 512
    ushort_t* fkH  = (ushort_t*)(fk2 + 512);               // 65536 u16
    ushort_t* f16  = fkH + 65536;                          // 4*NG*32 u16 = 28.3 MB

    k_prep_w<<<3456, 256, 0, stream>>>(W0, Wp);
    k_cvt<<<1728, 256, 0, stream>>>(feats, f16);
    hipMemsetAsync(gsum, 0, 256 * sizeof(float), stream);
    k_conv<<<864, 128, 0, stream>>>(f16, Wp, b0, yb, gsum, gsq);
    k_finalize<<<1, 128, 0, stream>>>(gsum, gsq, mu, ivr);
    k_sample<<<NKP, 128, 0, stream>>>(kpts, yb, mu, ivr, fkH, fk2);
    k_attn<<<1728, 256, 0, stream>>>(yb, mu, ivr, fkH, fk2, disp, (float*)d_out);
}